// Round 1
// baseline (491.047 us; speedup 1.0000x reference)
//
#include <hip/hip_runtime.h>
#include <float.h>

// Problem constants
#define T_LEN 4096
#define N_WIN 3969          // T - L + 1
#define K_SH  128
#define L_SH  128
#define B_SZ  256
#define SEGS  4             // n-segments per batch
#define TILES_PER_SEG 8     // 8 tiles * 128 rows = 1024 rows/segment; 4*1024=4096 >= 3969
#define NTILE 128

#define NEG_INF (-3.402823466e38f)

// Branchless insert of v into descending top-5 (t0 >= t1 >= ... >= t4)
#define TOP5_INSERT(v)                                            \
    do {                                                          \
        float _b = fmaxf(t4, (v));                                \
        float _m;                                                 \
        _m = fmaxf(t3, _b); _b = fminf(t3, _b); t3 = _m;          \
        _m = fmaxf(t2, t3); t3 = fminf(t2, t3); t2 = _m;          \
        _m = fmaxf(t1, t2); t2 = fminf(t1, t2); t1 = _m;          \
        _m = fmaxf(t0, t1); t1 = fminf(t0, t1); t0 = _m;          \
        t4 = _b;                                                  \
    } while (0)

// Kernel A: center shapelets over l, store transposed sT[l][k]
__global__ void prep_s_kernel(const float* __restrict__ s, float* __restrict__ sT) {
    __shared__ float sm[L_SH];
    const int k = blockIdx.x;
    const int l = threadIdx.x;
    const float v = s[k * L_SH + l];
    sm[l] = v;
    __syncthreads();
    for (int off = 64; off > 0; off >>= 1) {
        if (l < off) sm[l] += sm[l + off];
        __syncthreads();
    }
    const float mean = sm[0] * (1.0f / 128.0f);
    sT[l * K_SH + k] = v - mean;
}

// Kernel B: fused correlation + running top-5 per (b, k, seg, half)
// Grid: (SEGS, B_SZ), block: 256 threads.
// LDS (single 64 KB buffer, overlaid):
//   during compute: [0..255] = x slice, [256..2303] = sT chunk (16 l-rows)
//   after compute:  [0..16383] = corr tile (128 n-rows x 128 k)
__global__ __launch_bounds__(256, 2)
void corr_topk_kernel(const float* __restrict__ x,
                      const float* __restrict__ sT,
                      float* __restrict__ part) {
    __shared__ float lds[16384];

    const int seg = blockIdx.x;
    const int b   = blockIdx.y;
    const int t   = threadIdx.x;

    // compute-phase mapping: 16 k-groups x 16 n-groups, 8x8 regs per thread
    const int tk = t & 15;
    const int tn = t >> 4;
    const int k0 = tk * 8;
    const int nl = tn * 8;

    // selection-phase mapping: column k, row-half h
    const int kcol = t & 127;
    const int h    = t >> 7;

    float t0 = NEG_INF, t1 = NEG_INF, t2 = NEG_INF, t3 = NEG_INF, t4 = NEG_INF;

    const float* __restrict__ xb = x + (size_t)b * T_LEN;

    for (int tile = 0; tile < TILES_PER_SEG; ++tile) {
        const int n0 = seg * (TILES_PER_SEG * NTILE) + tile * NTILE;

        __syncthreads();  // previous tile's selection done before overwriting LDS
        {
            const int gi = n0 + t;                    // need n0 .. n0+254
            lds[t] = (gi < T_LEN) ? xb[gi] : 0.0f;
        }

        float acc[8][8];
        #pragma unroll
        for (int i = 0; i < 8; ++i)
            #pragma unroll
            for (int j = 0; j < 8; ++j) acc[i][j] = 0.0f;

        for (int lc = 0; lc < L_SH; lc += 16) {
            __syncthreads();  // prior chunk consumed (and x staged, first iter)
            {   // stage sT rows [lc, lc+16): 2048 floats = 512 float4
                const float4* __restrict__ src = (const float4*)(sT + lc * K_SH);
                float4* dst = (float4*)(lds + 256);
                dst[t]       = src[t];
                dst[t + 256] = src[t + 256];
            }
            __syncthreads();

            float xw[8];
            #pragma unroll
            for (int i = 0; i < 8; ++i) xw[i] = lds[nl + lc + i];

            #pragma unroll
            for (int l = 0; l < 16; ++l) {
                const float* srow = lds + 256 + l * K_SH + k0;
                const float4 sa = *(const float4*)(srow);
                const float4 sb = *(const float4*)(srow + 4);
                const float sv[8] = {sa.x, sa.y, sa.z, sa.w, sb.x, sb.y, sb.z, sb.w};
                #pragma unroll
                for (int i = 0; i < 8; ++i)
                    #pragma unroll
                    for (int j = 0; j < 8; ++j)
                        acc[i][j] = fmaf(xw[i], sv[j], acc[i][j]);
                // slide window by one
                #pragma unroll
                for (int i = 0; i < 7; ++i) xw[i] = xw[i + 1];
                xw[7] = lds[nl + lc + l + 8];
            }
        }

        __syncthreads();  // all compute done; x/sT regions dead
        #pragma unroll
        for (int i = 0; i < 8; ++i) {
            float4* dst = (float4*)(lds + (nl + i) * K_SH + k0);
            dst[0] = make_float4(acc[i][0], acc[i][1], acc[i][2], acc[i][3]);
            dst[1] = make_float4(acc[i][4], acc[i][5], acc[i][6], acc[i][7]);
        }
        __syncthreads();  // corr tile visible

        const int rbase = h * 64;
        #pragma unroll 4
        for (int r = 0; r < 64; ++r) {
            const int n = n0 + rbase + r;
            const float v = (n < N_WIN) ? lds[(rbase + r) * K_SH + kcol] : NEG_INF;
            TOP5_INSERT(v);
        }
    }

    // partials laid out [seg*2+h][5][b*K + k] for coalesced merge reads
    const int bk = b * K_SH + kcol;
    const int sb = (seg * 2 + h) * 5;
    part[(size_t)(sb + 0) * (B_SZ * K_SH) + bk] = t0;
    part[(size_t)(sb + 1) * (B_SZ * K_SH) + bk] = t1;
    part[(size_t)(sb + 2) * (B_SZ * K_SH) + bk] = t2;
    part[(size_t)(sb + 3) * (B_SZ * K_SH) + bk] = t3;
    part[(size_t)(sb + 4) * (B_SZ * K_SH) + bk] = t4;
}

// Kernel C: merge SEGS*2 partial top-5 lists per (b,k), emit features
__global__ void merge_topk_kernel(const float* __restrict__ part, float* __restrict__ out) {
    const int gid = blockIdx.x * 256 + threadIdx.x;   // 0 .. 32767
    const int b = gid >> 7;
    const int k = gid & 127;

    float t0 = NEG_INF, t1 = NEG_INF, t2 = NEG_INF, t3 = NEG_INF, t4 = NEG_INF;
    for (int j = 0; j < SEGS * 2 * 5; ++j) {
        const float v = part[(size_t)j * (B_SZ * K_SH) + gid];
        TOP5_INSERT(v);
    }

    const float p1 = t0;
    const float p2 = t1;
    const float pmean = (t0 + t1 + t2 + t3 + t4) * 0.2f;
    float* ob = out + (size_t)b * (4 * K_SH);
    ob[k]             = p1;
    ob[K_SH + k]      = pmean;
    ob[2 * K_SH + k]  = p2;
    ob[3 * K_SH + k]  = fmaxf(p1 - p2, 0.0f);
}

extern "C" void kernel_launch(void* const* d_in, const int* in_sizes, int n_in,
                              void* d_out, int out_size, void* d_ws, size_t ws_size,
                              hipStream_t stream) {
    const float* x = (const float*)d_in[0];        // (256, 4096) fp32
    const float* s = (const float*)d_in[1];        // (128, 128)  fp32
    float* out = (float*)d_out;                    // (256, 512)  fp32

    // ws layout: sT (128*128 f32 = 64 KB) | partials (40 * 32768 f32 = 5.24 MB)
    float* sT   = (float*)d_ws;
    float* part = sT + (L_SH * K_SH);

    prep_s_kernel<<<K_SH, L_SH, 0, stream>>>(s, sT);
    corr_topk_kernel<<<dim3(SEGS, B_SZ), 256, 0, stream>>>(x, sT, part);
    merge_topk_kernel<<<(B_SZ * K_SH) / 256, 256, 0, stream>>>(part, out);
}

// Round 3
// 141.813 us; speedup vs baseline: 3.4626x; 3.4626x over previous
//
#include <hip/hip_runtime.h>

// Problem constants
#define T_LEN 4096
#define N_WIN 3969          // T - L + 1
#define K_SH  128
#define L_SH  128
#define B_SZ  256
#define SEGS  4             // n-segments per batch
#define TILES_PER_SEG 8     // 8 tiles * 128 rows = 1024 rows/segment
#define NTILE 128

#define S_STRIDE 136        // padded row stride (bf16 elems): 272 B, bank-balanced
#define X_COPIES 8
#define X_STRIDE 264        // bf16 elems per shifted x copy: 528 B, bank-balanced

#define NEG_INF (-3.402823466e38f)

typedef __attribute__((ext_vector_type(8))) __bf16 bf16x8;
typedef __attribute__((ext_vector_type(4))) float f32x4;

// RNE float->bf16 (inputs are finite normals; NaN path not needed)
__device__ __forceinline__ unsigned short f2bf(float f) {
    union { float f; unsigned int u; } c; c.f = f;
    unsigned int u = c.u + 0x7fff + ((c.u >> 16) & 1u);
    return (unsigned short)(u >> 16);
}

// Branchless insert of v into descending top-5
__device__ __forceinline__ void top5_insert(float v, float& t0, float& t1,
                                            float& t2, float& t3, float& t4) {
    float b = fmaxf(t4, v);
    float m;
    m = fmaxf(t3, b); b = fminf(t3, b); t3 = m;
    m = fmaxf(t2, t3); t3 = fminf(t2, t3); t2 = m;
    m = fmaxf(t1, t2); t2 = fminf(t1, t2); t1 = m;
    m = fmaxf(t0, t1); t1 = fminf(t0, t1); t0 = m;
    t4 = b;
}

// Kernel A: center shapelets over l, emit bf16 rows padded to S_STRIDE
__global__ void prep_s_kernel(const float* __restrict__ s, unsigned short* __restrict__ sPrep) {
    __shared__ float sm[L_SH];
    const int k = blockIdx.x;
    const int l = threadIdx.x;
    const float v = s[k * L_SH + l];
    sm[l] = v;
    __syncthreads();
    for (int off = 64; off > 0; off >>= 1) {
        if (l < off) sm[l] += sm[l + off];
        __syncthreads();
    }
    const float mean = sm[0] * (1.0f / 128.0f);
    sPrep[k * S_STRIDE + l] = f2bf(v - mean);
    if (l < S_STRIDE - L_SH) sPrep[k * S_STRIDE + L_SH + l] = 0;  // zero the pad
}

// Kernel B: MFMA correlation + register-resident running top-5.
// Grid (SEGS, B), 256 threads (4 waves). Wave w owns shapelet tiles kt = 2w, 2w+1.
// Per 128-row n-tile: stage x slice as 8 shifted bf16 copies; 14 unique Hankel
// A-frags (u = mt + 2c); 4 K-chunks x 16 MFMAs; select from acc registers.
__global__ __launch_bounds__(256, 2)
void corr_topk_kernel(const float* __restrict__ x,
                      const unsigned short* __restrict__ sPrep,
                      float* __restrict__ part) {
    __shared__ __align__(16) unsigned short ldsS[K_SH * S_STRIDE];      // 34816 B
    __shared__ __align__(16) unsigned short ldsX[X_COPIES * X_STRIDE];  //  4224 B

    const int seg = blockIdx.x;
    const int b   = blockIdx.y;
    const int t   = threadIdx.x;
    const int lane = t & 63;
    const int w    = t >> 6;          // wave id 0..3
    const int r    = lane & 15;       // MFMA free-dim lane index
    const int q    = lane >> 4;       // MFMA quad 0..3
    const int c7   = lane & 7;        // x-copy index
    const int ub   = (lane >> 3) & 1;

    // ---- load centered bf16 shapelets into LDS (once per block) ----
    {
        const uint4* __restrict__ src = (const uint4*)sPrep;
        uint4* dst = (uint4*)ldsS;
        for (int i = t; i < (K_SH * S_STRIDE * 2) / 16; i += 256) dst[i] = src[i];
    }

    const float* __restrict__ xb = x + (size_t)b * T_LEN;

    // two top-5 lists per lane: list0 -> ks = 32w + r, list1 -> ks = 32w + 16 + r
    float a0 = NEG_INF, a1 = NEG_INF, a2 = NEG_INF, a3 = NEG_INF, a4 = NEG_INF;
    float b0 = NEG_INF, b1 = NEG_INF, b2 = NEG_INF, b3 = NEG_INF, b4 = NEG_INF;

    for (int tile = 0; tile < TILES_PER_SEG; ++tile) {
        const int n0 = seg * (TILES_PER_SEG * NTILE) + tile * NTILE;

        __syncthreads();  // prior tile's A-frag reads done before x overwrite
        {
            const int gi = n0 + t;
            const float v = (gi < T_LEN) ? xb[gi] : 0.0f;
            const unsigned short bv = f2bf(v);
            #pragma unroll
            for (int a = 0; a < X_COPIES; ++a) {
                const int p = t - a;
                if (p >= 0 && p < X_STRIDE) ldsX[a * X_STRIDE + p] = bv;
            }
        }
        __syncthreads();

        // ---- load the 14 unique Hankel A-fragments ----
        bf16x8 afr[14];
        {
            const char* xbase = (const char*)ldsX + c7 * (X_STRIDE * 2) + 16 * q + 16 * ub;
            #pragma unroll
            for (int u = 0; u < 14; ++u) {
                const uint4 v = *(const uint4*)(xbase + 32 * u);
                afr[u] = __builtin_bit_cast(bf16x8, v);
            }
        }

        f32x4 acc[8][2];
        #pragma unroll
        for (int mt = 0; mt < 8; ++mt) {
            acc[mt][0] = (f32x4){0.f, 0.f, 0.f, 0.f};
            acc[mt][1] = (f32x4){0.f, 0.f, 0.f, 0.f};
        }

        // ---- 4 K-chunks of 32 ----
        #pragma unroll
        for (int c = 0; c < 4; ++c) {
            const char* sb = (const char*)ldsS + r * (S_STRIDE * 2) + 64 * c + 16 * q;
            const bf16x8 bf0 = __builtin_bit_cast(bf16x8,
                *(const uint4*)(sb + (2 * w)     * (16 * S_STRIDE * 2)));
            const bf16x8 bf1 = __builtin_bit_cast(bf16x8,
                *(const uint4*)(sb + (2 * w + 1) * (16 * S_STRIDE * 2)));
            #pragma unroll
            for (int mt = 0; mt < 8; ++mt) {
                acc[mt][0] = __builtin_amdgcn_mfma_f32_16x16x32_bf16(afr[mt + 2 * c], bf0, acc[mt][0], 0, 0, 0);
                acc[mt][1] = __builtin_amdgcn_mfma_f32_16x16x32_bf16(afr[mt + 2 * c], bf1, acc[mt][1], 0, 0, 0);
            }
        }

        // ---- register-resident selection ----
        // lane's acc rows: n = n0 + mt*16 + 4q + reg; col ks fixed per lane.
        #pragma unroll
        for (int mt = 0; mt < 8; ++mt) {
            const int limit = N_WIN - (n0 + mt * 16 + 4 * q);  // reg < limit is valid
            #pragma unroll
            for (int reg = 0; reg < 4; ++reg) {
                {
                    const float v = acc[mt][0][reg];
                    if (v > a4 && reg < limit) top5_insert(v, a0, a1, a2, a3, a4);
                }
                {
                    const float v = acc[mt][1][reg];
                    if (v > b4 && reg < limit) top5_insert(v, b0, b1, b2, b3, b4);
                }
            }
        }
    }

    // ---- butterfly merge across quads (rows are quad-partitioned) ----
    // NOTE: snapshot ALL partner values BEFORE any insert — both lanes of an
    // XOR pair mutate their lists concurrently; reading partner state after
    // an insert duplicates the max and loses true elements (round-2 bug).
    #pragma unroll
    for (int mask = 16; mask <= 32; mask <<= 1) {
        const float sa0 = __shfl_xor(a0, mask);
        const float sa1 = __shfl_xor(a1, mask);
        const float sa2 = __shfl_xor(a2, mask);
        const float sa3 = __shfl_xor(a3, mask);
        const float sa4 = __shfl_xor(a4, mask);
        const float sb0 = __shfl_xor(b0, mask);
        const float sb1 = __shfl_xor(b1, mask);
        const float sb2 = __shfl_xor(b2, mask);
        const float sb3 = __shfl_xor(b3, mask);
        const float sb4 = __shfl_xor(b4, mask);
        top5_insert(sa0, a0, a1, a2, a3, a4);
        top5_insert(sa1, a0, a1, a2, a3, a4);
        top5_insert(sa2, a0, a1, a2, a3, a4);
        top5_insert(sa3, a0, a1, a2, a3, a4);
        top5_insert(sa4, a0, a1, a2, a3, a4);
        top5_insert(sb0, b0, b1, b2, b3, b4);
        top5_insert(sb1, b0, b1, b2, b3, b4);
        top5_insert(sb2, b0, b1, b2, b3, b4);
        top5_insert(sb3, b0, b1, b2, b3, b4);
        top5_insert(sb4, b0, b1, b2, b3, b4);
    }

    // partials: part[(seg*5 + j)*(B*K) + b*K + ks]
    const size_t plane = (size_t)B_SZ * K_SH;
    if (q == 0) {
        const int ks = 32 * w + r;
        float* p = part + (size_t)b * K_SH + ks + (size_t)(seg * 5) * plane;
        p[0] = a0; p[plane] = a1; p[2 * plane] = a2; p[3 * plane] = a3; p[4 * plane] = a4;
    } else if (q == 1) {
        const int ks = 32 * w + 16 + r;
        float* p = part + (size_t)b * K_SH + ks + (size_t)(seg * 5) * plane;
        p[0] = b0; p[plane] = b1; p[2 * plane] = b2; p[3 * plane] = b3; p[4 * plane] = b4;
    }
}

// Kernel C: merge SEGS partial top-5 lists per (b,ks), emit features
__global__ void merge_topk_kernel(const float* __restrict__ part, float* __restrict__ out) {
    const int gid = blockIdx.x * 256 + threadIdx.x;   // 0 .. 32767
    const int b = gid >> 7;
    const int k = gid & 127;

    float t0 = NEG_INF, t1 = NEG_INF, t2 = NEG_INF, t3 = NEG_INF, t4 = NEG_INF;
    for (int j = 0; j < SEGS * 5; ++j) {
        const float v = part[(size_t)j * (B_SZ * K_SH) + gid];
        top5_insert(v, t0, t1, t2, t3, t4);
    }

    const float p1 = t0;
    const float p2 = t1;
    const float pmean = (t0 + t1 + t2 + t3 + t4) * 0.2f;
    float* ob = out + (size_t)b * (4 * K_SH);
    ob[k]            = p1;
    ob[K_SH + k]     = pmean;
    ob[2 * K_SH + k] = p2;
    ob[3 * K_SH + k] = fmaxf(p1 - p2, 0.0f);
}

extern "C" void kernel_launch(void* const* d_in, const int* in_sizes, int n_in,
                              void* d_out, int out_size, void* d_ws, size_t ws_size,
                              hipStream_t stream) {
    const float* x = (const float*)d_in[0];        // (256, 4096) fp32
    const float* s = (const float*)d_in[1];        // (128, 128)  fp32
    float* out = (float*)d_out;                    // (256, 512)  fp32

    // ws layout: sPrep bf16 padded (128*136*2 = 34816 B, rounded to 40960)
    //          | partials (SEGS*5 * 32768 f32 = 2.62 MB)
    unsigned short* sPrep = (unsigned short*)d_ws;
    float* part = (float*)((char*)d_ws + 40960);

    prep_s_kernel<<<K_SH, L_SH, 0, stream>>>(s, sPrep);
    corr_topk_kernel<<<dim3(SEGS, B_SZ), 256, 0, stream>>>(x, sPrep, part);
    merge_topk_kernel<<<(B_SZ * K_SH) / 256, 256, 0, stream>>>(part, out);
}

// Round 4
// 133.395 us; speedup vs baseline: 3.6811x; 1.0631x over previous
//
#include <hip/hip_runtime.h>

// Problem constants
#define T_LEN 4096
#define N_WIN 3969          // T - L + 1
#define K_SH  128
#define L_SH  128
#define B_SZ  256
#define NT    31            // full 128-row n-tiles (n 0..3967); n=3968 special-cased

#define SSTR  136           // S row stride (bf16 elems), 272 B
#define XSTR  4104          // x copy stride (bf16 elems), 8208 B, 16B-aligned shifts

#define NEG_INF (-3.402823466e38f)

typedef __attribute__((ext_vector_type(8))) __bf16 bf16x8;
typedef __attribute__((ext_vector_type(4))) float f32x4;

__device__ __forceinline__ unsigned short f2bf(float f) {
    union { float f; unsigned int u; } c; c.f = f;
    unsigned int u = c.u + 0x7fff + ((c.u >> 16) & 1u);
    return (unsigned short)(u >> 16);
}
__device__ __forceinline__ unsigned int pack2(unsigned short lo, unsigned short hi) {
    return (unsigned int)lo | ((unsigned int)hi << 16);
}

// Branchless insert of v into descending top-5
__device__ __forceinline__ void top5_insert(float v, float& t0, float& t1,
                                            float& t2, float& t3, float& t4) {
    float b = fmaxf(t4, v);
    float m;
    m = fmaxf(t3, b); b = fminf(t3, b); t3 = m;
    m = fmaxf(t2, t3); t3 = fminf(t2, t3); t2 = m;
    m = fmaxf(t1, t2); t2 = fminf(t1, t2); t1 = m;
    m = fmaxf(t0, t1); t1 = fminf(t0, t1); t0 = m;
    t4 = b;
}

// Single fused kernel: grid = B (256 blocks, 1/CU), 512 threads (8 waves).
// Wave w: mh = w>>2 picks mt-half {0..3}/{4..7}; wp = w&3 picks kt pair {2wp, 2wp+1}.
// LDS: ldsS = centered bf16 shapelets (B operand, read once into regs);
//      ldsX = 8 shifted bf16 copies of the whole x row (Hankel A fragments are
//      then single aligned ds_read_b128). Tile loop has NO barriers.
__global__ __launch_bounds__(512, 1)
void shapelet_fused_kernel(const float* __restrict__ x,
                           const float* __restrict__ s,
                           float* __restrict__ out) {
    __shared__ __align__(16) unsigned short ldsS[K_SH * SSTR];   // 34816 B
    __shared__ __align__(16) unsigned short ldsX[8 * XSTR];      // 65664 B

    const int t    = threadIdx.x;
    const int lane = t & 63;
    const int w    = t >> 6;
    const int r    = lane & 15;       // MFMA free-dim lane index (col for B/C, row for A)
    const int q    = lane >> 4;       // MFMA quad
    const int c7   = lane & 7;        // x-copy index
    const int ub   = (lane >> 3) & 1;
    const int mh   = w >> 2;          // mt-half: mt in [4*mh, 4*mh+4)
    const int wp   = w & 3;           // kt pair: kts {2wp, 2wp+1}
    const int mtb  = 4 * mh;
    const int b    = blockIdx.x;

    // ---- stage centered S as bf16 (fused prep): thread -> (row k, quarter qd) ----
    {
        const int k = t >> 2, qd = t & 3;
        const float4* srow = (const float4*)(s + k * L_SH + qd * 32);
        float4 v[8];
        float sum = 0.0f;
        #pragma unroll
        for (int j = 0; j < 8; ++j) {
            v[j] = srow[j];
            sum += (v[j].x + v[j].y) + (v[j].z + v[j].w);
        }
        sum += __shfl_xor(sum, 1);
        sum += __shfl_xor(sum, 2);
        const float mean = sum * (1.0f / 128.0f);
        uint4* dst = (uint4*)((char*)ldsS + k * (SSTR * 2) + qd * 64);
        #pragma unroll
        for (int j = 0; j < 4; ++j) {
            uint4 o;
            o.x = pack2(f2bf(v[2*j].x - mean),   f2bf(v[2*j].y - mean));
            o.y = pack2(f2bf(v[2*j].z - mean),   f2bf(v[2*j].w - mean));
            o.z = pack2(f2bf(v[2*j+1].x - mean), f2bf(v[2*j+1].y - mean));
            o.w = pack2(f2bf(v[2*j+1].z - mean), f2bf(v[2*j+1].w - mean));
            dst[j] = o;
        }
        if (qd == 3) *(uint4*)((char*)ldsS + k * (SSTR * 2) + 256) = make_uint4(0,0,0,0);
    }

    // ---- stage whole x row as 8 shifted bf16 copies (once per block) ----
    {
        const float* __restrict__ xb = x + (size_t)b * T_LEN;
        for (int i = t; i < XSTR / 8; i += 512) {           // 513 8-elem chunks per copy
            const int p0 = 8 * i;
            float xv[16];
            if (p0 + 16 <= T_LEN) {
                const float4* sp = (const float4*)(xb + p0);
                #pragma unroll
                for (int j = 0; j < 4; ++j) *(float4*)(xv + 4 * j) = sp[j];
            } else {
                #pragma unroll
                for (int j = 0; j < 16; ++j) {
                    const int gi = p0 + j;
                    xv[j] = (gi < T_LEN) ? xb[gi] : 0.0f;
                }
            }
            unsigned short bv[16];
            #pragma unroll
            for (int j = 0; j < 16; ++j) bv[j] = f2bf(xv[j]);
            #pragma unroll
            for (int a = 0; a < 8; ++a) {                   // copy a elem p holds x[p+a]
                uint4 o;
                o.x = pack2(bv[a],     bv[a + 1]);
                o.y = pack2(bv[a + 2], bv[a + 3]);
                o.z = pack2(bv[a + 4], bv[a + 5]);
                o.w = pack2(bv[a + 6], bv[a + 7]);
                *(uint4*)((char*)ldsX + a * (XSTR * 2) + 2 * p0) = o;
            }
        }
    }
    __syncthreads();

    // ---- hoist B fragments (shapelets) to registers: 2 kts x 4 K-chunks ----
    bf16x8 bfr[2][4];
    #pragma unroll
    for (int kk = 0; kk < 2; ++kk)
        #pragma unroll
        for (int c = 0; c < 4; ++c)
            bfr[kk][c] = __builtin_bit_cast(bf16x8, *(const uint4*)(
                (const char*)ldsS + ((2 * wp + kk) * 16 + r) * (SSTR * 2) + 64 * c + 16 * q));

    // top-5 lists: a -> ks = 32*wp + r, b -> ks = 32*wp + 16 + r (rows mt in mh half)
    float a0 = NEG_INF, a1 = NEG_INF, a2 = NEG_INF, a3 = NEG_INF, a4 = NEG_INF;
    float b0 = NEG_INF, b1 = NEG_INF, b2 = NEG_INF, b3 = NEG_INF, b4 = NEG_INF;

    // ---- barrier-free tile loop: 31 tiles x (10 A-frag ds_reads + 32 MFMA + select) ----
    const char* xptr = (const char*)ldsX + c7 * (XSTR * 2) + 16 * q + 16 * ub + 32 * mtb;
    for (int tile = 0; tile < NT; ++tile) {
        bf16x8 afr[10];                 // u = (mt-mtb) + 2c in [0,10)
        #pragma unroll
        for (int j = 0; j < 10; ++j)
            afr[j] = __builtin_bit_cast(bf16x8, *(const uint4*)(xptr + 32 * j));
        xptr += 256;                    // 128 elems per tile

        f32x4 acc0[4], acc1[4];
        #pragma unroll
        for (int m = 0; m < 4; ++m) {
            acc0[m] = (f32x4){0.f, 0.f, 0.f, 0.f};
            acc1[m] = (f32x4){0.f, 0.f, 0.f, 0.f};
        }
        #pragma unroll
        for (int c = 0; c < 4; ++c) {
            #pragma unroll
            for (int m = 0; m < 4; ++m) {
                acc0[m] = __builtin_amdgcn_mfma_f32_16x16x32_bf16(afr[m + 2 * c], bfr[0][c], acc0[m], 0, 0, 0);
                acc1[m] = __builtin_amdgcn_mfma_f32_16x16x32_bf16(afr[m + 2 * c], bfr[1][c], acc1[m], 0, 0, 0);
            }
        }

        // hierarchical selection: group max then guarded per-value insert
        #pragma unroll
        for (int m = 0; m < 4; ++m) {
            {
                const f32x4 A = acc0[m];
                const float g = fmaxf(fmaxf(A[0], A[1]), fmaxf(A[2], A[3]));
                if (g > a4) {
                    #pragma unroll
                    for (int reg = 0; reg < 4; ++reg) {
                        const float v = A[reg];
                        if (v > a4) top5_insert(v, a0, a1, a2, a3, a4);
                    }
                }
            }
            {
                const f32x4 A = acc1[m];
                const float g = fmaxf(fmaxf(A[0], A[1]), fmaxf(A[2], A[3]));
                if (g > b4) {
                    #pragma unroll
                    for (int reg = 0; reg < 4; ++reg) {
                        const float v = A[reg];
                        if (v > b4) top5_insert(v, b0, b1, b2, b3, b4);
                    }
                }
            }
        }
    }

    // ---- boundary row n = 3968 (only row 0 of a would-be tile 31, mt=0 -> mh==0) ----
    if (mh == 0) {
        f32x4 e0 = (f32x4){0.f, 0.f, 0.f, 0.f};
        f32x4 e1 = (f32x4){0.f, 0.f, 0.f, 0.f};
        const char* eb = (const char*)ldsX + c7 * (XSTR * 2) + 7936 + 16 * q + 16 * ub;
        #pragma unroll
        for (int c = 0; c < 4; ++c) {
            const bf16x8 af = __builtin_bit_cast(bf16x8, *(const uint4*)(eb + 64 * c));
            e0 = __builtin_amdgcn_mfma_f32_16x16x32_bf16(af, bfr[0][c], e0, 0, 0, 0);
            e1 = __builtin_amdgcn_mfma_f32_16x16x32_bf16(af, bfr[1][c], e1, 0, 0, 0);
        }
        if (q == 0) {   // row = 4q + reg == 0 -> n = 3968
            const float v0 = e0[0];
            if (v0 > a4) top5_insert(v0, a0, a1, a2, a3, a4);
            const float v1 = e1[0];
            if (v1 > b4) top5_insert(v1, b0, b1, b2, b3, b4);
        }
    }

    // ---- butterfly merge across quads (snapshot partner BEFORE inserting!) ----
    #pragma unroll
    for (int mask = 16; mask <= 32; mask <<= 1) {
        const float sa0 = __shfl_xor(a0, mask), sa1 = __shfl_xor(a1, mask);
        const float sa2 = __shfl_xor(a2, mask), sa3 = __shfl_xor(a3, mask);
        const float sa4 = __shfl_xor(a4, mask);
        const float sb0 = __shfl_xor(b0, mask), sb1 = __shfl_xor(b1, mask);
        const float sb2 = __shfl_xor(b2, mask), sb3 = __shfl_xor(b3, mask);
        const float sb4 = __shfl_xor(b4, mask);
        top5_insert(sa0, a0, a1, a2, a3, a4);
        top5_insert(sa1, a0, a1, a2, a3, a4);
        top5_insert(sa2, a0, a1, a2, a3, a4);
        top5_insert(sa3, a0, a1, a2, a3, a4);
        top5_insert(sa4, a0, a1, a2, a3, a4);
        top5_insert(sb0, b0, b1, b2, b3, b4);
        top5_insert(sb1, b0, b1, b2, b3, b4);
        top5_insert(sb2, b0, b1, b2, b3, b4);
        top5_insert(sb3, b0, b1, b2, b3, b4);
        top5_insert(sb4, b0, b1, b2, b3, b4);
    }

    // ---- cross-mh merge via LDS (ldsS region is dead; reuse as scratch) ----
    __syncthreads();
    float* mbuf = (float*)ldsS;    // [ks][5]
    if (mh == 1) {
        if (q == 0) {
            const int ks = 32 * wp + r;
            float* p = mbuf + ks * 5;
            p[0] = a0; p[1] = a1; p[2] = a2; p[3] = a3; p[4] = a4;
        } else if (q == 1) {
            const int ks = 32 * wp + 16 + r;
            float* p = mbuf + ks * 5;
            p[0] = b0; p[1] = b1; p[2] = b2; p[3] = b3; p[4] = b4;
        }
    }
    __syncthreads();
    if (mh == 0) {
        float* ob = out + (size_t)b * (4 * K_SH);
        if (q == 0) {
            const int ks = 32 * wp + r;
            const float* p = mbuf + ks * 5;
            top5_insert(p[0], a0, a1, a2, a3, a4);
            top5_insert(p[1], a0, a1, a2, a3, a4);
            top5_insert(p[2], a0, a1, a2, a3, a4);
            top5_insert(p[3], a0, a1, a2, a3, a4);
            top5_insert(p[4], a0, a1, a2, a3, a4);
            const float p1 = a0, p2 = a1;
            const float pmean = (((a0 + a1) + (a2 + a3)) + a4) * 0.2f;
            ob[ks]           = p1;
            ob[K_SH + ks]    = pmean;
            ob[2*K_SH + ks]  = p2;
            ob[3*K_SH + ks]  = fmaxf(p1 - p2, 0.0f);
        } else if (q == 1) {
            const int ks = 32 * wp + 16 + r;
            const float* p = mbuf + ks * 5;
            top5_insert(p[0], b0, b1, b2, b3, b4);
            top5_insert(p[1], b0, b1, b2, b3, b4);
            top5_insert(p[2], b0, b1, b2, b3, b4);
            top5_insert(p[3], b0, b1, b2, b3, b4);
            top5_insert(p[4], b0, b1, b2, b3, b4);
            const float p1 = b0, p2 = b1;
            const float pmean = (((b0 + b1) + (b2 + b3)) + b4) * 0.2f;
            ob[ks]           = p1;
            ob[K_SH + ks]    = pmean;
            ob[2*K_SH + ks]  = p2;
            ob[3*K_SH + ks]  = fmaxf(p1 - p2, 0.0f);
        }
    }
}

extern "C" void kernel_launch(void* const* d_in, const int* in_sizes, int n_in,
                              void* d_out, int out_size, void* d_ws, size_t ws_size,
                              hipStream_t stream) {
    const float* x = (const float*)d_in[0];        // (256, 4096) fp32
    const float* s = (const float*)d_in[1];        // (128, 128)  fp32
    float* out = (float*)d_out;                    // (256, 512)  fp32
    shapelet_fused_kernel<<<B_SZ, 512, 0, stream>>>(x, s, out);
}

// Round 5
// 108.671 us; speedup vs baseline: 4.5187x; 1.2275x over previous
//
#include <hip/hip_runtime.h>

// Problem constants
#define T_LEN 4096
#define N_WIN 3969          // T - L + 1
#define K_SH  128
#define L_SH  128
#define B_SZ  256
#define NT    31            // full 128-row n-tiles (n 0..3967); n=3968 special-cased

#define SSTR  136           // S row stride (bf16 elems), 272 B
// x copy stride (bf16): 8720 B. stride/4 = 2180 ≡ 4 (mod 32) -> the 8 copy bases
// land on distinct banks {0,4,..,28}. Padded past 4104 so tile-31 prefetch
// (max byte 8304) stays in range. Total LDS 34816 + 69760 = 104576 B.
#define XSTR  4360

#define NEG_INF (-3.402823466e38f)

typedef __attribute__((ext_vector_type(8))) __bf16 bf16x8;
typedef __attribute__((ext_vector_type(4))) float f32x4;

__device__ __forceinline__ unsigned short f2bf(float f) {
    union { float f; unsigned int u; } c; c.f = f;
    unsigned int u = c.u + 0x7fff + ((c.u >> 16) & 1u);
    return (unsigned short)(u >> 16);
}
__device__ __forceinline__ unsigned int pack2(unsigned short lo, unsigned short hi) {
    return (unsigned int)lo | ((unsigned int)hi << 16);
}

// compare-exchange: hi = max, lo = min (branchless, 2 ops)
__device__ __forceinline__ void ce(float& hi, float& lo) {
    const float m = fmaxf(hi, lo);
    lo = fminf(hi, lo);
    hi = m;
}
// descending sort of 4 (optimal 5-comparator network)
__device__ __forceinline__ void sort4(float& a, float& b, float& c, float& d) {
    ce(a, b); ce(c, d); ce(a, c); ce(b, d); ce(b, c);
}
// top-5 of two descending sorted 4-lists (odd-even merge, 8 comparators)
__device__ __forceinline__ void merge44_top5(float a0, float a1, float a2, float a3,
                                             float b0, float b1, float b2, float b3,
                                             float& r0, float& r1, float& r2, float& r3, float& r4) {
    ce(a0, b0); ce(a2, b2); ce(b0, a2);   // odds sorted:  a0,b0,a2,b2
    ce(a1, b1); ce(a3, b3); ce(b1, a3);   // evens sorted: a1,b1,a3,b3
    r0 = a0;
    r1 = a1; r2 = b0; ce(r1, r2);
    r3 = b1; r4 = a2; ce(r3, r4);
}
// r = top-5 of union of two descending sorted 5-lists r, s.
// Sorted-merge identity: c_k = max over i+j=k of min(a_i, b_j).
__device__ __forceinline__ void merge55(float& r0, float& r1, float& r2, float& r3, float& r4,
                                        float s0, float s1, float s2, float s3, float s4) {
    const float m00 = fminf(r0, s0);
    const float m10 = fminf(r1, s0), m01 = fminf(r0, s1);
    const float m20 = fminf(r2, s0), m11 = fminf(r1, s1), m02 = fminf(r0, s2);
    const float m30 = fminf(r3, s0), m21 = fminf(r2, s1), m12 = fminf(r1, s2), m03 = fminf(r0, s3);
    const float n0 = fmaxf(r0, s0);
    const float n1 = fmaxf(fmaxf(r1, s1), m00);
    const float n2 = fmaxf(fmaxf(r2, s2), fmaxf(m10, m01));
    const float n3 = fmaxf(fmaxf(fmaxf(r3, s3), m20), fmaxf(m11, m02));
    const float n4 = fmaxf(fmaxf(fmaxf(r4, s4), fmaxf(m30, m03)), fmaxf(m21, m12));
    r0 = n0; r1 = n1; r2 = n2; r3 = n3; r4 = n4;
}
// single-value insert (epilogue only)
__device__ __forceinline__ void top5_insert(float v, float& t0, float& t1,
                                            float& t2, float& t3, float& t4) {
    float b = fmaxf(t4, v);
    float m;
    m = fmaxf(t3, b);  b  = fminf(t3, b);  t3 = m;
    m = fmaxf(t2, t3); t3 = fminf(t2, t3); t2 = m;
    m = fmaxf(t1, t2); t2 = fminf(t1, t2); t1 = m;
    m = fmaxf(t0, t1); t1 = fminf(t0, t1); t0 = m;
    t4 = b;
}

// Single fused kernel: grid = B (256 blocks, 1/CU), 512 threads (8 waves).
// Wave w: mh = w>>2 picks mt-half; wp = w&3 picks kt pair {2wp, 2wp+1}.
__global__ __launch_bounds__(512, 1)
void shapelet_fused_kernel(const float* __restrict__ x,
                           const float* __restrict__ s,
                           float* __restrict__ out) {
    __shared__ __align__(16) unsigned short ldsS[K_SH * SSTR];   // 34816 B
    __shared__ __align__(16) unsigned short ldsX[8 * XSTR];      // 69760 B

    const int t    = threadIdx.x;
    const int lane = t & 63;
    const int w    = t >> 6;
    const int r    = lane & 15;
    const int q    = lane >> 4;
    const int c7   = lane & 7;
    const int ub   = (lane >> 3) & 1;
    const int mh   = w >> 2;
    const int wp   = w & 3;
    const int mtb  = 4 * mh;
    const int b    = blockIdx.x;

    // ---- stage centered S as bf16 (fused prep): thread -> (row k, quarter qd) ----
    {
        const int k = t >> 2, qd = t & 3;
        const float4* srow = (const float4*)(s + k * L_SH + qd * 32);
        float4 v[8];
        float sum = 0.0f;
        #pragma unroll
        for (int j = 0; j < 8; ++j) {
            v[j] = srow[j];
            sum += (v[j].x + v[j].y) + (v[j].z + v[j].w);
        }
        sum += __shfl_xor(sum, 1);
        sum += __shfl_xor(sum, 2);
        const float mean = sum * (1.0f / 128.0f);
        uint4* dst = (uint4*)((char*)ldsS + k * (SSTR * 2) + qd * 64);
        #pragma unroll
        for (int j = 0; j < 4; ++j) {
            uint4 o;
            o.x = pack2(f2bf(v[2*j].x - mean),   f2bf(v[2*j].y - mean));
            o.y = pack2(f2bf(v[2*j].z - mean),   f2bf(v[2*j].w - mean));
            o.z = pack2(f2bf(v[2*j+1].x - mean), f2bf(v[2*j+1].y - mean));
            o.w = pack2(f2bf(v[2*j+1].z - mean), f2bf(v[2*j+1].w - mean));
            dst[j] = o;
        }
        if (qd == 3) *(uint4*)((char*)ldsS + k * (SSTR * 2) + 256) = make_uint4(0,0,0,0);
    }

    // ---- stage x row as 8 shifted bf16 copies; thread -> (copy = t&7, chunk) ----
    // copy a, element p holds x[p+a]; lane-consecutive chunks within one copy
    // keep ds_write bank phases near the b128 minimum (round-4 pattern was 16-way).
    {
        const float* __restrict__ xb = x + (size_t)b * T_LEN;
        const int a = t & 7;
        for (int i = (t >> 3); i < XSTR / 8; i += 64) {
            const int p0 = 8 * i;
            float xv[16];
            if (p0 + 16 <= T_LEN) {
                const float4* sp = (const float4*)(xb + p0);
                #pragma unroll
                for (int j = 0; j < 4; ++j) *(float4*)(xv + 4 * j) = sp[j];
            } else {
                #pragma unroll
                for (int j = 0; j < 16; ++j) {
                    const int gi = p0 + j;
                    xv[j] = (gi < T_LEN) ? xb[gi] : 0.0f;
                }
            }
            unsigned short bv[16];
            #pragma unroll
            for (int j = 0; j < 16; ++j) bv[j] = f2bf(xv[j]);
            uint4 o;
            o.x = pack2(bv[a],     bv[a + 1]);
            o.y = pack2(bv[a + 2], bv[a + 3]);
            o.z = pack2(bv[a + 4], bv[a + 5]);
            o.w = pack2(bv[a + 6], bv[a + 7]);
            *(uint4*)((char*)ldsX + a * (XSTR * 2) + 2 * p0) = o;
        }
    }
    __syncthreads();

    // ---- hoist B fragments (shapelets) to registers: 2 kts x 4 K-chunks ----
    bf16x8 bfr[2][4];
    #pragma unroll
    for (int kk = 0; kk < 2; ++kk)
        #pragma unroll
        for (int c = 0; c < 4; ++c)
            bfr[kk][c] = __builtin_bit_cast(bf16x8, *(const uint4*)(
                (const char*)ldsS + ((2 * wp + kk) * 16 + r) * (SSTR * 2) + 64 * c + 16 * q));

    // running top-5 lists: a -> ks = 32*wp + r, b -> ks = 32*wp + 16 + r
    float a0 = NEG_INF, a1 = NEG_INF, a2 = NEG_INF, a3 = NEG_INF, a4 = NEG_INF;
    float b0 = NEG_INF, b1 = NEG_INF, b2 = NEG_INF, b3 = NEG_INF, b4 = NEG_INF;

    const char* xp = (const char*)ldsX + c7 * (XSTR * 2) + 16 * q + 16 * ub + 32 * mtb;

    // double-buffered A fragments (10 unique Hankel frags / wave / tile)
    bf16x8 afrA[10], afrB[10];
    #pragma unroll
    for (int j = 0; j < 10; ++j)
        afrA[j] = __builtin_bit_cast(bf16x8, *(const uint4*)(xp + 32 * j));

    int off = 256;   // byte offset of NEXT tile's frags relative to xp

    // tile body: MFMA on CUR -> prefetch NXT -> branchless selection
#define TILE_STEP(CUR, NXT)                                                     \
    {                                                                           \
        f32x4 acc0[4], acc1[4];                                                 \
        _Pragma("unroll")                                                       \
        for (int m = 0; m < 4; ++m) {                                           \
            acc0[m] = (f32x4){0.f, 0.f, 0.f, 0.f};                              \
            acc1[m] = (f32x4){0.f, 0.f, 0.f, 0.f};                              \
        }                                                                       \
        _Pragma("unroll")                                                       \
        for (int c = 0; c < 4; ++c) {                                           \
            _Pragma("unroll")                                                   \
            for (int m = 0; m < 4; ++m) {                                       \
                acc0[m] = __builtin_amdgcn_mfma_f32_16x16x32_bf16(CUR[m + 2*c], bfr[0][c], acc0[m], 0, 0, 0); \
                acc1[m] = __builtin_amdgcn_mfma_f32_16x16x32_bf16(CUR[m + 2*c], bfr[1][c], acc1[m], 0, 0, 0); \
            }                                                                   \
        }                                                                       \
        _Pragma("unroll")                                                       \
        for (int j = 0; j < 10; ++j)                                            \
            NXT[j] = __builtin_bit_cast(bf16x8, *(const uint4*)(xp + off + 32 * j)); \
        off += 256;                                                             \
        {   /* list a: 16 values from acc0 */                                   \
            float p0=acc0[0][0], p1=acc0[0][1], p2=acc0[0][2], p3=acc0[0][3];   \
            float q0=acc0[1][0], q1=acc0[1][1], q2=acc0[1][2], q3=acc0[1][3];   \
            sort4(p0,p1,p2,p3); sort4(q0,q1,q2,q3);                             \
            float u0,u1,u2,u3,u4;                                               \
            merge44_top5(p0,p1,p2,p3, q0,q1,q2,q3, u0,u1,u2,u3,u4);             \
            float x0=acc0[2][0], x1=acc0[2][1], x2=acc0[2][2], x3=acc0[2][3];   \
            float y0=acc0[3][0], y1=acc0[3][1], y2=acc0[3][2], y3=acc0[3][3];   \
            sort4(x0,x1,x2,x3); sort4(y0,y1,y2,y3);                             \
            float v0,v1,v2,v3,v4;                                               \
            merge44_top5(x0,x1,x2,x3, y0,y1,y2,y3, v0,v1,v2,v3,v4);             \
            merge55(u0,u1,u2,u3,u4, v0,v1,v2,v3,v4);                            \
            merge55(a0,a1,a2,a3,a4, u0,u1,u2,u3,u4);                            \
        }                                                                       \
        {   /* list b: 16 values from acc1 */                                   \
            float p0=acc1[0][0], p1=acc1[0][1], p2=acc1[0][2], p3=acc1[0][3];   \
            float q0=acc1[1][0], q1=acc1[1][1], q2=acc1[1][2], q3=acc1[1][3];   \
            sort4(p0,p1,p2,p3); sort4(q0,q1,q2,q3);                             \
            float u0,u1,u2,u3,u4;                                               \
            merge44_top5(p0,p1,p2,p3, q0,q1,q2,q3, u0,u1,u2,u3,u4);             \
            float x0=acc1[2][0], x1=acc1[2][1], x2=acc1[2][2], x3=acc1[2][3];   \
            float y0=acc1[3][0], y1=acc1[3][1], y2=acc1[3][2], y3=acc1[3][3];   \
            sort4(x0,x1,x2,x3); sort4(y0,y1,y2,y3);                             \
            float v0,v1,v2,v3,v4;                                               \
            merge44_top5(x0,x1,x2,x3, y0,y1,y2,y3, v0,v1,v2,v3,v4);             \
            merge55(u0,u1,u2,u3,u4, v0,v1,v2,v3,v4);                            \
            merge55(b0,b1,b2,b3,b4, u0,u1,u2,u3,u4);                            \
        }                                                                       \
    }

    for (int tt = 0; tt < 15; ++tt) {
        TILE_STEP(afrA, afrB)
        TILE_STEP(afrB, afrA)
    }
    TILE_STEP(afrA, afrB)   // tile 30; prefetch reads padded tile-31 region (unused)
#undef TILE_STEP

    // ---- boundary row n = 3968 (row 0 of would-be tile 31; mt=0 -> mh==0) ----
    if (mh == 0) {
        f32x4 e0 = (f32x4){0.f, 0.f, 0.f, 0.f};
        f32x4 e1 = (f32x4){0.f, 0.f, 0.f, 0.f};
        const char* eb = (const char*)ldsX + c7 * (XSTR * 2) + 7936 + 16 * q + 16 * ub;
        #pragma unroll
        for (int c = 0; c < 4; ++c) {
            const bf16x8 af = __builtin_bit_cast(bf16x8, *(const uint4*)(eb + 64 * c));
            e0 = __builtin_amdgcn_mfma_f32_16x16x32_bf16(af, bfr[0][c], e0, 0, 0, 0);
            e1 = __builtin_amdgcn_mfma_f32_16x16x32_bf16(af, bfr[1][c], e1, 0, 0, 0);
        }
        if (q == 0) {   // row = 4q + reg == 0 -> n = 3968
            const float v0 = e0[0];
            if (v0 > a4) top5_insert(v0, a0, a1, a2, a3, a4);
            const float v1 = e1[0];
            if (v1 > b4) top5_insert(v1, b0, b1, b2, b3, b4);
        }
    }

    // ---- butterfly merge across quads (snapshot BEFORE merging!) ----
    #pragma unroll
    for (int mask = 16; mask <= 32; mask <<= 1) {
        const float sa0 = __shfl_xor(a0, mask), sa1 = __shfl_xor(a1, mask);
        const float sa2 = __shfl_xor(a2, mask), sa3 = __shfl_xor(a3, mask);
        const float sa4 = __shfl_xor(a4, mask);
        const float sb0 = __shfl_xor(b0, mask), sb1 = __shfl_xor(b1, mask);
        const float sb2 = __shfl_xor(b2, mask), sb3 = __shfl_xor(b3, mask);
        const float sb4 = __shfl_xor(b4, mask);
        merge55(a0, a1, a2, a3, a4, sa0, sa1, sa2, sa3, sa4);
        merge55(b0, b1, b2, b3, b4, sb0, sb1, sb2, sb3, sb4);
    }

    // ---- cross-mh merge via LDS (ldsS dead after bfr hoist; reuse) ----
    __syncthreads();
    float* mbuf = (float*)ldsS;    // [ks][5]
    if (mh == 1) {
        if (q == 0) {
            const int ks = 32 * wp + r;
            float* p = mbuf + ks * 5;
            p[0] = a0; p[1] = a1; p[2] = a2; p[3] = a3; p[4] = a4;
        } else if (q == 1) {
            const int ks = 32 * wp + 16 + r;
            float* p = mbuf + ks * 5;
            p[0] = b0; p[1] = b1; p[2] = b2; p[3] = b3; p[4] = b4;
        }
    }
    __syncthreads();
    if (mh == 0) {
        float* ob = out + (size_t)b * (4 * K_SH);
        if (q == 0) {
            const int ks = 32 * wp + r;
            const float* p = mbuf + ks * 5;
            merge55(a0, a1, a2, a3, a4, p[0], p[1], p[2], p[3], p[4]);
            const float p1 = a0, p2 = a1;
            const float pmean = (((a0 + a1) + (a2 + a3)) + a4) * 0.2f;
            ob[ks]            = p1;
            ob[K_SH + ks]     = pmean;
            ob[2*K_SH + ks]   = p2;
            ob[3*K_SH + ks]   = fmaxf(p1 - p2, 0.0f);
        } else if (q == 1) {
            const int ks = 32 * wp + 16 + r;
            const float* p = mbuf + ks * 5;
            merge55(b0, b1, b2, b3, b4, p[0], p[1], p[2], p[3], p[4]);
            const float p1 = b0, p2 = b1;
            const float pmean = (((b0 + b1) + (b2 + b3)) + b4) * 0.2f;
            ob[ks]            = p1;
            ob[K_SH + ks]     = pmean;
            ob[2*K_SH + ks]   = p2;
            ob[3*K_SH + ks]   = fmaxf(p1 - p2, 0.0f);
        }
    }
}

extern "C" void kernel_launch(void* const* d_in, const int* in_sizes, int n_in,
                              void* d_out, int out_size, void* d_ws, size_t ws_size,
                              hipStream_t stream) {
    const float* x = (const float*)d_in[0];        // (256, 4096) fp32
    const float* s = (const float*)d_in[1];        // (128, 128)  fp32
    float* out = (float*)d_out;                    // (256, 512)  fp32
    shapelet_fused_kernel<<<B_SZ, 512, 0, stream>>>(x, s, out);
}

// Round 7
// 96.610 us; speedup vs baseline: 5.0828x; 1.1248x over previous
//
#include <hip/hip_runtime.h>

// Problem constants
#define T_LEN 4096
#define N_WIN 3969          // T - L + 1
#define K_SH  128
#define L_SH  128
#define B_SZ  256
#define NT    31            // full 128-row n-tiles (n 0..3967); n=3968 special-cased

#define SSTR  136           // S row stride (bf16 elems), 272 B
// x copy stride (bf16): 8720 B; stride/4 ≡ 4 (mod 32) -> 8 copy bases on distinct
// banks. Padded so tile-30's prefetch of "tile 31" stays in range.
#define XSTR  4360

#define NEG_INF (-3.402823466e38f)

typedef __attribute__((ext_vector_type(8))) __bf16 bf16x8;
typedef __attribute__((ext_vector_type(4))) float f32x4;
typedef _Float16 h2 __attribute__((ext_vector_type(2)));   // packed half pair

__device__ __forceinline__ unsigned short f2bf(float f) {
    union { float f; unsigned int u; } c; c.f = f;
    unsigned int u = c.u + 0x7fff + ((c.u >> 16) & 1u);
    return (unsigned short)(u >> 16);
}
__device__ __forceinline__ unsigned int pack2(unsigned short lo, unsigned short hi) {
    return (unsigned int)lo | ((unsigned int)hi << 16);
}

// ---- packed-f16 selection primitives (each op handles BOTH lists) ----
__device__ __forceinline__ h2 max2(h2 a, h2 b) { return __builtin_elementwise_max(a, b); }
__device__ __forceinline__ h2 min2(h2 a, h2 b) { return __builtin_elementwise_min(a, b); }
__device__ __forceinline__ h2 cvt2(float lo, float hi) {   // lo -> elem0, hi -> elem1
    return __builtin_bit_cast(h2, __builtin_amdgcn_cvt_pkrtz(lo, hi));
}
__device__ __forceinline__ void ce2(h2& hi, h2& lo) {
    const h2 m = max2(hi, lo);
    lo = min2(hi, lo);
    hi = m;
}
__device__ __forceinline__ void sort4_2(h2& a, h2& b, h2& c, h2& d) {
    ce2(a, b); ce2(c, d); ce2(a, c); ce2(b, d); ce2(b, c);
}
// top-5 of two descending sorted 4-lists (odd-even merge, 8 comparators)
__device__ __forceinline__ void merge44_top5_2(h2 a0, h2 a1, h2 a2, h2 a3,
                                               h2 b0, h2 b1, h2 b2, h2 b3,
                                               h2& r0, h2& r1, h2& r2, h2& r3, h2& r4) {
    ce2(a0, b0); ce2(a2, b2); ce2(b0, a2);
    ce2(a1, b1); ce2(a3, b3); ce2(b1, a3);
    r0 = a0;
    r1 = a1; r2 = b0; ce2(r1, r2);
    r3 = b1; r4 = a2; ce2(r3, r4);
}
// r = top-5 of union of two descending sorted 5-lists (c_k = max_{i+j=k} min(a_i,b_j))
__device__ __forceinline__ void merge55_2(h2& r0, h2& r1, h2& r2, h2& r3, h2& r4,
                                          h2 s0, h2 s1, h2 s2, h2 s3, h2 s4) {
    const h2 m00 = min2(r0, s0);
    const h2 m10 = min2(r1, s0), m01 = min2(r0, s1);
    const h2 m20 = min2(r2, s0), m11 = min2(r1, s1), m02 = min2(r0, s2);
    const h2 m30 = min2(r3, s0), m21 = min2(r2, s1), m12 = min2(r1, s2), m03 = min2(r0, s3);
    const h2 n0 = max2(r0, s0);
    const h2 n1 = max2(max2(r1, s1), m00);
    const h2 n2 = max2(max2(r2, s2), max2(m10, m01));
    const h2 n3 = max2(max2(max2(r3, s3), m20), max2(m11, m02));
    const h2 n4 = max2(max2(max2(r4, s4), max2(m30, m03)), max2(m21, m12));
    r0 = n0; r1 = n1; r2 = n2; r3 = n3; r4 = n4;
}
// packed single-value insert (epilogue only)
__device__ __forceinline__ void insert1_2(h2 v, h2* rt) {
    h2 b = max2(rt[4], v); h2 m;
    m = max2(rt[3], b);     b     = min2(rt[3], b);     rt[3] = m;
    m = max2(rt[2], rt[3]); rt[3] = min2(rt[2], rt[3]); rt[2] = m;
    m = max2(rt[1], rt[2]); rt[2] = min2(rt[1], rt[2]); rt[1] = m;
    m = max2(rt[0], rt[1]); rt[1] = min2(rt[0], rt[1]); rt[0] = m;
    rt[4] = b;
}
// per-tile: fold 32 acc values (16 per list) into packed running top-5
__device__ __forceinline__ void select32(const f32x4* acc0, const f32x4* acc1, h2* rt) {
    h2 p[16];
    #pragma unroll
    for (int m = 0; m < 4; ++m)
        #pragma unroll
        for (int i = 0; i < 4; ++i)
            p[4 * m + i] = cvt2(acc0[m][i], acc1[m][i]);
    sort4_2(p[0], p[1], p[2],  p[3]);
    sort4_2(p[4], p[5], p[6],  p[7]);
    sort4_2(p[8], p[9], p[10], p[11]);
    sort4_2(p[12], p[13], p[14], p[15]);
    h2 u0, u1, u2, u3, u4, v0, v1, v2, v3, v4;
    merge44_top5_2(p[0], p[1], p[2],  p[3],  p[4],  p[5],  p[6],  p[7],  u0, u1, u2, u3, u4);
    merge44_top5_2(p[8], p[9], p[10], p[11], p[12], p[13], p[14], p[15], v0, v1, v2, v3, v4);
    merge55_2(u0, u1, u2, u3, u4, v0, v1, v2, v3, v4);
    merge55_2(rt[0], rt[1], rt[2], rt[3], rt[4], u0, u1, u2, u3, u4);
}

// Single fused kernel: grid = B (256 blocks, 1/CU), 512 threads (8 waves).
// Wave w: mh = w>>2 picks mt-half; wp = w&3 picks kt pair {2wp, 2wp+1}.
__global__ __launch_bounds__(512, 1)
void shapelet_fused_kernel(const float* __restrict__ x,
                           const float* __restrict__ s,
                           float* __restrict__ out) {
    __shared__ __align__(16) unsigned short ldsS[K_SH * SSTR];   // 34816 B
    __shared__ __align__(16) unsigned short ldsX[8 * XSTR];      // 69760 B

    const int t    = threadIdx.x;
    const int lane = t & 63;
    const int w    = t >> 6;
    const int r    = lane & 15;
    const int q    = lane >> 4;
    const int c7   = lane & 7;
    const int ub   = (lane >> 3) & 1;
    const int mh   = w >> 2;
    const int wp   = w & 3;
    const int mtb  = 4 * mh;
    const int b    = blockIdx.x;

    // ---- stage centered S as bf16 (fused prep): thread -> (row k, quarter qd) ----
    {
        const int k = t >> 2, qd = t & 3;
        const float4* srow = (const float4*)(s + k * L_SH + qd * 32);
        float4 v[8];
        float sum = 0.0f;
        #pragma unroll
        for (int j = 0; j < 8; ++j) {
            v[j] = srow[j];
            sum += (v[j].x + v[j].y) + (v[j].z + v[j].w);
        }
        sum += __shfl_xor(sum, 1);
        sum += __shfl_xor(sum, 2);
        const float mean = sum * (1.0f / 128.0f);
        uint4* dst = (uint4*)((char*)ldsS + k * (SSTR * 2) + qd * 64);
        #pragma unroll
        for (int j = 0; j < 4; ++j) {
            uint4 o;
            o.x = pack2(f2bf(v[2*j].x - mean),   f2bf(v[2*j].y - mean));
            o.y = pack2(f2bf(v[2*j].z - mean),   f2bf(v[2*j].w - mean));
            o.z = pack2(f2bf(v[2*j+1].x - mean), f2bf(v[2*j+1].y - mean));
            o.w = pack2(f2bf(v[2*j+1].z - mean), f2bf(v[2*j+1].w - mean));
            dst[j] = o;
        }
        if (qd == 3) *(uint4*)((char*)ldsS + k * (SSTR * 2) + 256) = make_uint4(0,0,0,0);
    }

    // ---- stage x row as 8 shifted bf16 copies; thread -> (copy = t&7, chunk) ----
    {
        const float* __restrict__ xb = x + (size_t)b * T_LEN;
        const int a = t & 7;
        for (int i = (t >> 3); i < XSTR / 8; i += 64) {
            const int p0 = 8 * i;
            float xv[16];
            if (p0 + 16 <= T_LEN) {
                const float4* sp = (const float4*)(xb + p0);
                #pragma unroll
                for (int j = 0; j < 4; ++j) *(float4*)(xv + 4 * j) = sp[j];
            } else {
                #pragma unroll
                for (int j = 0; j < 16; ++j) {
                    const int gi = p0 + j;
                    xv[j] = (gi < T_LEN) ? xb[gi] : 0.0f;
                }
            }
            unsigned short bv[16];
            #pragma unroll
            for (int j = 0; j < 16; ++j) bv[j] = f2bf(xv[j]);
            uint4 o;
            o.x = pack2(bv[a],     bv[a + 1]);
            o.y = pack2(bv[a + 2], bv[a + 3]);
            o.z = pack2(bv[a + 4], bv[a + 5]);
            o.w = pack2(bv[a + 6], bv[a + 7]);
            *(uint4*)((char*)ldsX + a * (XSTR * 2) + 2 * p0) = o;
        }
    }
    __syncthreads();

    // ---- hoist B fragments (shapelets) to registers: 2 kts x 4 K-chunks ----
    bf16x8 bfr[2][4];
    #pragma unroll
    for (int kk = 0; kk < 2; ++kk)
        #pragma unroll
        for (int c = 0; c < 4; ++c)
            bfr[kk][c] = __builtin_bit_cast(bf16x8, *(const uint4*)(
                (const char*)ldsS + ((2 * wp + kk) * 16 + r) * (SSTR * 2) + 64 * c + 16 * q));

    // packed running top-5: elem0 -> ks = 32*wp + r, elem1 -> ks = 32*wp + 16 + r
    h2 rt[5];
    #pragma unroll
    for (int i = 0; i < 5; ++i) rt[i] = __builtin_bit_cast(h2, 0xFC00FC00u);  // (-inf,-inf)

    const char* xp = (const char*)ldsX + c7 * (XSTR * 2) + 16 * q + 16 * ub + 32 * mtb;

    // double-buffered A fragments (10 unique Hankel frags / wave / tile)
    bf16x8 afrA[10], afrB[10];
    #pragma unroll
    for (int j = 0; j < 10; ++j)
        afrA[j] = __builtin_bit_cast(bf16x8, *(const uint4*)(xp + 32 * j));

    int off = 256;   // byte offset of NEXT tile's frags relative to xp

#define TILE_STEP(CUR, NXT)                                                     \
    {                                                                           \
        f32x4 acc0[4], acc1[4];                                                 \
        _Pragma("unroll")                                                       \
        for (int m = 0; m < 4; ++m) {                                           \
            acc0[m] = (f32x4){0.f, 0.f, 0.f, 0.f};                              \
            acc1[m] = (f32x4){0.f, 0.f, 0.f, 0.f};                              \
        }                                                                       \
        _Pragma("unroll")                                                       \
        for (int c = 0; c < 4; ++c) {                                           \
            _Pragma("unroll")                                                   \
            for (int m = 0; m < 4; ++m) {                                       \
                acc0[m] = __builtin_amdgcn_mfma_f32_16x16x32_bf16(CUR[m + 2*c], bfr[0][c], acc0[m], 0, 0, 0); \
                acc1[m] = __builtin_amdgcn_mfma_f32_16x16x32_bf16(CUR[m + 2*c], bfr[1][c], acc1[m], 0, 0, 0); \
            }                                                                   \
        }                                                                       \
        _Pragma("unroll")                                                       \
        for (int j = 0; j < 10; ++j)                                            \
            NXT[j] = __builtin_bit_cast(bf16x8, *(const uint4*)(xp + off + 32 * j)); \
        off += 256;                                                             \
        select32(acc0, acc1, rt);                                               \
    }

    for (int tt = 0; tt < 15; ++tt) {
        TILE_STEP(afrA, afrB)
        TILE_STEP(afrB, afrA)
    }
    TILE_STEP(afrA, afrB)   // tile 30; prefetch reads padded region (unused)
#undef TILE_STEP

    // ---- boundary row n = 3968 (row 0 of would-be tile 31; mt=0 -> mh==0) ----
    if (mh == 0) {
        f32x4 e0 = (f32x4){0.f, 0.f, 0.f, 0.f};
        f32x4 e1 = (f32x4){0.f, 0.f, 0.f, 0.f};
        const char* eb = (const char*)ldsX + c7 * (XSTR * 2) + 7936 + 16 * q + 16 * ub;
        #pragma unroll
        for (int c = 0; c < 4; ++c) {
            const bf16x8 af = __builtin_bit_cast(bf16x8, *(const uint4*)(eb + 64 * c));
            e0 = __builtin_amdgcn_mfma_f32_16x16x32_bf16(af, bfr[0][c], e0, 0, 0, 0);
            e1 = __builtin_amdgcn_mfma_f32_16x16x32_bf16(af, bfr[1][c], e1, 0, 0, 0);
        }
        if (q == 0) insert1_2(cvt2(e0[0], e1[0]), rt);   // n = 3968 for both lists
    }

    // ---- butterfly merge across quads (snapshot BEFORE merging) ----
    #pragma unroll
    for (int mask = 16; mask <= 32; mask <<= 1) {
        h2 s[5];
        #pragma unroll
        for (int i = 0; i < 5; ++i)
            s[i] = __builtin_bit_cast(h2, __shfl_xor(__builtin_bit_cast(int, rt[i]), mask));
        merge55_2(rt[0], rt[1], rt[2], rt[3], rt[4], s[0], s[1], s[2], s[3], s[4]);
    }

    // ---- cross-mh merge via LDS (ldsS dead after bfr hoist; reuse, packed u32) ----
    __syncthreads();
    unsigned int* pbuf = (unsigned int*)ldsS;   // [wp*16 + r][5]
    if (mh == 1 && q == 0) {
        unsigned int* p = pbuf + (wp * 16 + r) * 5;
        #pragma unroll
        for (int i = 0; i < 5; ++i) p[i] = __builtin_bit_cast(unsigned int, rt[i]);
    }
    __syncthreads();
    if (mh == 0 && q == 0) {
        const unsigned int* p = pbuf + (wp * 16 + r) * 5;
        h2 s[5];
        #pragma unroll
        for (int i = 0; i < 5; ++i) s[i] = __builtin_bit_cast(h2, p[i]);
        merge55_2(rt[0], rt[1], rt[2], rt[3], rt[4], s[0], s[1], s[2], s[3], s[4]);

        // unpack both lists; lane emits features for ksA = 32wp+r and ksB = ksA+16
        const float A0 = (float)rt[0][0], A1 = (float)rt[1][0], A2 = (float)rt[2][0],
                    A3 = (float)rt[3][0], A4 = (float)rt[4][0];
        const float B0 = (float)rt[0][1], B1 = (float)rt[1][1], B2 = (float)rt[2][1],
                    B3 = (float)rt[3][1], B4 = (float)rt[4][1];
        float* ob = out + (size_t)b * (4 * K_SH);
        const int ksA = 32 * wp + r, ksB = ksA + 16;
        const float mA = (((A0 + A1) + (A2 + A3)) + A4) * 0.2f;
        const float mB = (((B0 + B1) + (B2 + B3)) + B4) * 0.2f;
        ob[ksA]           = A0;
        ob[K_SH + ksA]    = mA;
        ob[2*K_SH + ksA]  = A1;
        ob[3*K_SH + ksA]  = fmaxf(A0 - A1, 0.0f);
        ob[ksB]           = B0;
        ob[K_SH + ksB]    = mB;
        ob[2*K_SH + ksB]  = B1;
        ob[3*K_SH + ksB]  = fmaxf(B0 - B1, 0.0f);
    }
}

extern "C" void kernel_launch(void* const* d_in, const int* in_sizes, int n_in,
                              void* d_out, int out_size, void* d_ws, size_t ws_size,
                              hipStream_t stream) {
    const float* x = (const float*)d_in[0];        // (256, 4096) fp32
    const float* s = (const float*)d_in[1];        // (128, 128)  fp32
    float* out = (float*)d_out;                    // (256, 512)  fp32
    shapelet_fused_kernel<<<B_SZ, 512, 0, stream>>>(x, s, out);
}

// Round 8
// 94.703 us; speedup vs baseline: 5.1851x; 1.0201x over previous
//
#include <hip/hip_runtime.h>

// Problem constants
#define T_LEN 4096
#define N_WIN 3969          // T - L + 1
#define K_SH  128
#define L_SH  128
#define B_SZ  256

#define SSTR  136           // S row stride (bf16 elems), 272 B
// x copy stride (bf16): 8720 B; stride/4 ≡ 4 (mod 32) -> 8 copy bases on distinct
// banks. Padded so the last tile's reads stay in range.
#define XSTR  4360

typedef __attribute__((ext_vector_type(8))) __bf16 bf16x8;
typedef __attribute__((ext_vector_type(4))) float f32x4;
typedef _Float16 h2 __attribute__((ext_vector_type(2)));   // packed half pair

__device__ __forceinline__ unsigned short f2bf(float f) {
    union { float f; unsigned int u; } c; c.f = f;
    unsigned int u = c.u + 0x7fff + ((c.u >> 16) & 1u);
    return (unsigned short)(u >> 16);
}
__device__ __forceinline__ unsigned int pack2(unsigned short lo, unsigned short hi) {
    return (unsigned int)lo | ((unsigned int)hi << 16);
}

// ---- packed-f16 selection primitives (each op handles BOTH lists) ----
__device__ __forceinline__ h2 max2(h2 a, h2 b) { return __builtin_elementwise_max(a, b); }
__device__ __forceinline__ h2 min2(h2 a, h2 b) { return __builtin_elementwise_min(a, b); }
__device__ __forceinline__ h2 cvt2(float lo, float hi) {   // lo -> elem0, hi -> elem1
    return __builtin_bit_cast(h2, __builtin_amdgcn_cvt_pkrtz(lo, hi));
}
__device__ __forceinline__ void ce2(h2& hi, h2& lo) {
    const h2 m = max2(hi, lo);
    lo = min2(hi, lo);
    hi = m;
}
__device__ __forceinline__ void sort4_2(h2& a, h2& b, h2& c, h2& d) {
    ce2(a, b); ce2(c, d); ce2(a, c); ce2(b, d); ce2(b, c);
}
// top-5 of two descending sorted 4-lists (odd-even merge, 8 comparators)
__device__ __forceinline__ void merge44_top5_2(h2 a0, h2 a1, h2 a2, h2 a3,
                                               h2 b0, h2 b1, h2 b2, h2 b3,
                                               h2& r0, h2& r1, h2& r2, h2& r3, h2& r4) {
    ce2(a0, b0); ce2(a2, b2); ce2(b0, a2);
    ce2(a1, b1); ce2(a3, b3); ce2(b1, a3);
    r0 = a0;
    r1 = a1; r2 = b0; ce2(r1, r2);
    r3 = b1; r4 = a2; ce2(r3, r4);
}
// r = top-5 of union of two descending sorted 5-lists (c_k = max_{i+j=k} min(a_i,b_j))
__device__ __forceinline__ void merge55_2(h2& r0, h2& r1, h2& r2, h2& r3, h2& r4,
                                          h2 s0, h2 s1, h2 s2, h2 s3, h2 s4) {
    const h2 m00 = min2(r0, s0);
    const h2 m10 = min2(r1, s0), m01 = min2(r0, s1);
    const h2 m20 = min2(r2, s0), m11 = min2(r1, s1), m02 = min2(r0, s2);
    const h2 m30 = min2(r3, s0), m21 = min2(r2, s1), m12 = min2(r1, s2), m03 = min2(r0, s3);
    const h2 n0 = max2(r0, s0);
    const h2 n1 = max2(max2(r1, s1), m00);
    const h2 n2 = max2(max2(r2, s2), max2(m10, m01));
    const h2 n3 = max2(max2(max2(r3, s3), m20), max2(m11, m02));
    const h2 n4 = max2(max2(max2(r4, s4), max2(m30, m03)), max2(m21, m12));
    r0 = n0; r1 = n1; r2 = n2; r3 = n3; r4 = n4;
}
// packed single-value insert (epilogue only)
__device__ __forceinline__ void insert1_2(h2 v, h2* rt) {
    h2 b = max2(rt[4], v); h2 m;
    m = max2(rt[3], b);     b     = min2(rt[3], b);     rt[3] = m;
    m = max2(rt[2], rt[3]); rt[3] = min2(rt[2], rt[3]); rt[2] = m;
    m = max2(rt[1], rt[2]); rt[2] = min2(rt[1], rt[2]); rt[1] = m;
    m = max2(rt[0], rt[1]); rt[1] = min2(rt[0], rt[1]); rt[0] = m;
    rt[4] = b;
}
// per-tile: fold 32 acc values (16 per list) into packed running top-5
__device__ __forceinline__ void select32(const f32x4* acc0, const f32x4* acc1, h2* rt) {
    h2 p[16];
    #pragma unroll
    for (int m = 0; m < 4; ++m)
        #pragma unroll
        for (int i = 0; i < 4; ++i)
            p[4 * m + i] = cvt2(acc0[m][i], acc1[m][i]);
    sort4_2(p[0], p[1], p[2],  p[3]);
    sort4_2(p[4], p[5], p[6],  p[7]);
    sort4_2(p[8], p[9], p[10], p[11]);
    sort4_2(p[12], p[13], p[14], p[15]);
    h2 u0, u1, u2, u3, u4, v0, v1, v2, v3, v4;
    merge44_top5_2(p[0], p[1], p[2],  p[3],  p[4],  p[5],  p[6],  p[7],  u0, u1, u2, u3, u4);
    merge44_top5_2(p[8], p[9], p[10], p[11], p[12], p[13], p[14], p[15], v0, v1, v2, v3, v4);
    merge55_2(u0, u1, u2, u3, u4, v0, v1, v2, v3, v4);
    merge55_2(rt[0], rt[1], rt[2], rt[3], rt[4], u0, u1, u2, u3, u4);
}

// Single fused kernel: grid = B (256 blocks), 1024 threads (16 waves, 4/SIMD).
// Wave w: g = w>>3 tile-parity group (g=0 even tiles, g=1 odd tiles);
// within group: mh = (w>>2)&1 mt-half, wp = w&3 kt pair {2wp, 2wp+1}.
__global__ __launch_bounds__(1024)
void shapelet_fused_kernel(const float* __restrict__ x,
                           const float* __restrict__ s,
                           float* __restrict__ out) {
    __shared__ __align__(16) unsigned short ldsS[K_SH * SSTR];   // 34816 B
    __shared__ __align__(16) unsigned short ldsX[8 * XSTR];      // 69760 B

    const int t    = threadIdx.x;
    const int lane = t & 63;
    const int w    = t >> 6;
    const int r    = lane & 15;
    const int q    = lane >> 4;
    const int c7   = lane & 7;
    const int ub   = (lane >> 3) & 1;
    const int g    = w >> 3;          // tile-parity group
    const int w7   = w & 7;
    const int mh   = w7 >> 2;
    const int wp   = w7 & 3;
    const int mtb  = 4 * mh;
    const int b    = blockIdx.x;

    // ---- stage centered S as bf16: 8 threads per row k, 16 elems each ----
    {
        const int k = t >> 3, e8 = t & 7;
        const float4* srow = (const float4*)(s + k * L_SH + e8 * 16);
        float4 v[4];
        float sum = 0.0f;
        #pragma unroll
        for (int j = 0; j < 4; ++j) {
            v[j] = srow[j];
            sum += (v[j].x + v[j].y) + (v[j].z + v[j].w);
        }
        sum += __shfl_xor(sum, 1);
        sum += __shfl_xor(sum, 2);
        sum += __shfl_xor(sum, 4);
        const float mean = sum * (1.0f / 128.0f);
        uint4* dst = (uint4*)((char*)ldsS + k * (SSTR * 2) + e8 * 32);
        #pragma unroll
        for (int j = 0; j < 2; ++j) {
            uint4 o;
            o.x = pack2(f2bf(v[2*j].x - mean),   f2bf(v[2*j].y - mean));
            o.y = pack2(f2bf(v[2*j].z - mean),   f2bf(v[2*j].w - mean));
            o.z = pack2(f2bf(v[2*j+1].x - mean), f2bf(v[2*j+1].y - mean));
            o.w = pack2(f2bf(v[2*j+1].z - mean), f2bf(v[2*j+1].w - mean));
            dst[j] = o;
        }
        if (e8 == 7) *(uint4*)((char*)ldsS + k * (SSTR * 2) + 256) = make_uint4(0,0,0,0);
    }

    // ---- stage x row as 8 shifted bf16 copies; thread -> (copy = t&7, chunk) ----
    {
        const float* __restrict__ xb = x + (size_t)b * T_LEN;
        const int a = t & 7;
        for (int i = (t >> 3); i < XSTR / 8; i += 128) {
            const int p0 = 8 * i;
            float xv[16];
            if (p0 + 16 <= T_LEN) {
                const float4* sp = (const float4*)(xb + p0);
                #pragma unroll
                for (int j = 0; j < 4; ++j) *(float4*)(xv + 4 * j) = sp[j];
            } else {
                #pragma unroll
                for (int j = 0; j < 16; ++j) {
                    const int gi = p0 + j;
                    xv[j] = (gi < T_LEN) ? xb[gi] : 0.0f;
                }
            }
            unsigned short bv[16];
            #pragma unroll
            for (int j = 0; j < 16; ++j) bv[j] = f2bf(xv[j]);
            uint4 o;
            o.x = pack2(bv[a],     bv[a + 1]);
            o.y = pack2(bv[a + 2], bv[a + 3]);
            o.z = pack2(bv[a + 4], bv[a + 5]);
            o.w = pack2(bv[a + 6], bv[a + 7]);
            *(uint4*)((char*)ldsX + a * (XSTR * 2) + 2 * p0) = o;
        }
    }
    __syncthreads();

    // ---- hoist B fragments (shapelets) to registers: 2 kts x 4 K-chunks ----
    bf16x8 bfr[2][4];
    #pragma unroll
    for (int kk = 0; kk < 2; ++kk)
        #pragma unroll
        for (int c = 0; c < 4; ++c)
            bfr[kk][c] = __builtin_bit_cast(bf16x8, *(const uint4*)(
                (const char*)ldsS + ((2 * wp + kk) * 16 + r) * (SSTR * 2) + 64 * c + 16 * q));

    // packed running top-5: elem0 -> ks = 32*wp + r, elem1 -> ks = 32*wp + 16 + r
    h2 rt[5];
    #pragma unroll
    for (int i = 0; i < 5; ++i) rt[i] = __builtin_bit_cast(h2, 0xFC00FC00u);  // (-inf,-inf)

    // group g starts at tile g; advances by 2 tiles (512 B) per step
    const char* xp = (const char*)ldsX + c7 * (XSTR * 2) + 16 * q + 16 * ub + 32 * mtb
                   + g * 256;

    // single-buffer A fragments (10 unique Hankel frags / wave / tile);
    // 4 waves/SIMD provide the latency hiding the double buffer used to.
#define TILE_STEP                                                               \
    {                                                                           \
        bf16x8 afr[10];                                                         \
        _Pragma("unroll")                                                       \
        for (int j = 0; j < 10; ++j)                                            \
            afr[j] = __builtin_bit_cast(bf16x8, *(const uint4*)(xp + 32 * j));  \
        xp += 512;                                                              \
        f32x4 acc0[4], acc1[4];                                                 \
        _Pragma("unroll")                                                       \
        for (int m = 0; m < 4; ++m) {                                           \
            acc0[m] = (f32x4){0.f, 0.f, 0.f, 0.f};                              \
            acc1[m] = (f32x4){0.f, 0.f, 0.f, 0.f};                              \
        }                                                                       \
        _Pragma("unroll")                                                       \
        for (int c = 0; c < 4; ++c) {                                           \
            _Pragma("unroll")                                                   \
            for (int m = 0; m < 4; ++m) {                                       \
                acc0[m] = __builtin_amdgcn_mfma_f32_16x16x32_bf16(afr[m + 2*c], bfr[0][c], acc0[m], 0, 0, 0); \
                acc1[m] = __builtin_amdgcn_mfma_f32_16x16x32_bf16(afr[m + 2*c], bfr[1][c], acc1[m], 0, 0, 0); \
            }                                                                   \
        }                                                                       \
        select32(acc0, acc1, rt);                                               \
    }

    // g=0: tiles 0,2,...,30 (16 steps); g=1: tiles 1,3,...,29 (15 steps)
    for (int st = 0; st < 15; ++st) { TILE_STEP }
    if (g == 0) { TILE_STEP }
#undef TILE_STEP

    // ---- boundary row n = 3968 (row 0 of would-be tile 31) -> group 1, mh 0 ----
    if (g == 1 && mh == 0) {
        f32x4 e0 = (f32x4){0.f, 0.f, 0.f, 0.f};
        f32x4 e1 = (f32x4){0.f, 0.f, 0.f, 0.f};
        const char* eb = (const char*)ldsX + c7 * (XSTR * 2) + 7936 + 16 * q + 16 * ub;
        #pragma unroll
        for (int c = 0; c < 4; ++c) {
            const bf16x8 af = __builtin_bit_cast(bf16x8, *(const uint4*)(eb + 64 * c));
            e0 = __builtin_amdgcn_mfma_f32_16x16x32_bf16(af, bfr[0][c], e0, 0, 0, 0);
            e1 = __builtin_amdgcn_mfma_f32_16x16x32_bf16(af, bfr[1][c], e1, 0, 0, 0);
        }
        if (q == 0) insert1_2(cvt2(e0[0], e1[0]), rt);   // n = 3968 for both lists
    }

    // ---- butterfly merge across quads (snapshot BEFORE merging) ----
    #pragma unroll
    for (int mask = 16; mask <= 32; mask <<= 1) {
        h2 sv[5];
        #pragma unroll
        for (int i = 0; i < 5; ++i)
            sv[i] = __builtin_bit_cast(h2, __shfl_xor(__builtin_bit_cast(int, rt[i]), mask));
        merge55_2(rt[0], rt[1], rt[2], rt[3], rt[4], sv[0], sv[1], sv[2], sv[3], sv[4]);
    }

    // ---- cross-(g, mh) merge via LDS: 3 writer combos, reader (g=0, mh=0) ----
    __syncthreads();   // all bfr-hoist reads of ldsS long done; reuse as scratch
    unsigned int* pbuf = (unsigned int*)ldsS;   // [region][wp*16 + r][5]
    if ((g != 0 || mh != 0) && q == 0) {
        const int reg = (g * 2 + mh) - 1;       // 0..2
        unsigned int* p = pbuf + ((reg * 64) + wp * 16 + r) * 5;
        #pragma unroll
        for (int i = 0; i < 5; ++i) p[i] = __builtin_bit_cast(unsigned int, rt[i]);
    }
    __syncthreads();
    if (g == 0 && mh == 0 && q == 0) {
        #pragma unroll
        for (int reg = 0; reg < 3; ++reg) {
            const unsigned int* p = pbuf + ((reg * 64) + wp * 16 + r) * 5;
            h2 sv[5];
            #pragma unroll
            for (int i = 0; i < 5; ++i) sv[i] = __builtin_bit_cast(h2, p[i]);
            merge55_2(rt[0], rt[1], rt[2], rt[3], rt[4], sv[0], sv[1], sv[2], sv[3], sv[4]);
        }

        // unpack both lists; lane emits features for ksA = 32wp+r and ksB = ksA+16
        const float A0 = (float)rt[0][0], A1 = (float)rt[1][0], A2 = (float)rt[2][0],
                    A3 = (float)rt[3][0], A4 = (float)rt[4][0];
        const float B0 = (float)rt[0][1], B1 = (float)rt[1][1], B2 = (float)rt[2][1],
                    B3 = (float)rt[3][1], B4 = (float)rt[4][1];
        float* ob = out + (size_t)b * (4 * K_SH);
        const int ksA = 32 * wp + r, ksB = ksA + 16;
        const float mA = (((A0 + A1) + (A2 + A3)) + A4) * 0.2f;
        const float mB = (((B0 + B1) + (B2 + B3)) + B4) * 0.2f;
        ob[ksA]           = A0;
        ob[K_SH + ksA]    = mA;
        ob[2*K_SH + ksA]  = A1;
        ob[3*K_SH + ksA]  = fmaxf(A0 - A1, 0.0f);
        ob[ksB]           = B0;
        ob[K_SH + ksB]    = mB;
        ob[2*K_SH + ksB]  = B1;
        ob[3*K_SH + ksB]  = fmaxf(B0 - B1, 0.0f);
    }
}

extern "C" void kernel_launch(void* const* d_in, const int* in_sizes, int n_in,
                              void* d_out, int out_size, void* d_ws, size_t ws_size,
                              hipStream_t stream) {
    const float* x = (const float*)d_in[0];        // (256, 4096) fp32
    const float* s = (const float*)d_in[1];        // (128, 128)  fp32
    float* out = (float*)d_out;                    // (256, 512)  fp32
    shapelet_fused_kernel<<<B_SZ, 1024, 0, stream>>>(x, s, out);
}